// Round 1
// baseline (363.769 us; speedup 1.0000x reference)
//
#include <hip/hip_runtime.h>

// Problem constants (fixed by the reference): B=64, L=4096, D=256.
#define BB 64
#define LL 4096
#define DD 256
#define CHUNK 256
#define NCHUNK (LL / CHUNK) // 16

// Kernel 1: per (batch, chunk) block. Compute per-timestep dot(states, w) + b,
// then within-chunk inclusive suffix sum -> q; chunk total -> chunk_tot.
__global__ __launch_bounds__(256) void qval_chunk_kernel(
    const float* __restrict__ states, const float* __restrict__ w,
    const float* __restrict__ b_reward, float* __restrict__ q,
    float* __restrict__ chunk_tot) {
  const int c = blockIdx.x;     // chunk index within batch
  const int b = blockIdx.y;     // batch index
  const int tid = (int)threadIdx.x;
  const int wave = tid >> 6;    // 4 waves per block
  const int lane = tid & 63;

  __shared__ float vals[CHUNK];

  // Each lane owns 4 contiguous dims of w (D=256 = 64 lanes * 4).
  const float4 wv = ((const float4*)w)[lane];
  const float br = *b_reward;

  // Base of this block's chunk: states[b, c*CHUNK + r, :]
  const float4* sp =
      (const float4*)(states + ((size_t)b * LL + (size_t)c * CHUNK) * DD);

  // Wave `wave` handles rows [wave*64, wave*64+64); 4 rows per iteration
  // so 4 coalesced float4 loads are in flight before the shuffle chain.
  for (int i0 = 0; i0 < 64; i0 += 4) {
    const int r0 = wave * 64 + i0;
    float4 x0 = sp[(size_t)(r0 + 0) * 64 + lane];
    float4 x1 = sp[(size_t)(r0 + 1) * 64 + lane];
    float4 x2 = sp[(size_t)(r0 + 2) * 64 + lane];
    float4 x3 = sp[(size_t)(r0 + 3) * 64 + lane];
    float d0 = x0.x * wv.x + x0.y * wv.y + x0.z * wv.z + x0.w * wv.w;
    float d1 = x1.x * wv.x + x1.y * wv.y + x1.z * wv.z + x1.w * wv.w;
    float d2 = x2.x * wv.x + x2.y * wv.y + x2.z * wv.z + x2.w * wv.w;
    float d3 = x3.x * wv.x + x3.y * wv.y + x3.z * wv.z + x3.w * wv.w;
    // 64-lane butterfly-style reduction (shfl_down tree, width 64).
    for (int off = 32; off > 0; off >>= 1) {
      d0 += __shfl_down(d0, off, 64);
      d1 += __shfl_down(d1, off, 64);
      d2 += __shfl_down(d2, off, 64);
      d3 += __shfl_down(d3, off, 64);
    }
    if (lane == 0) {
      vals[r0 + 0] = d0 + br;
      vals[r0 + 1] = d1 + br;
      vals[r0 + 2] = d2 + br;
      vals[r0 + 3] = d3 + br;
    }
  }
  __syncthreads();

  // Inclusive suffix scan over the 256 chunk values (Hillis-Steele, 8 steps).
  for (int off = 1; off < CHUNK; off <<= 1) {
    float v = vals[tid];
    float a = (tid + off < CHUNK) ? vals[tid + off] : 0.0f;
    __syncthreads();
    vals[tid] = v + a;
    __syncthreads();
  }

  q[(size_t)b * LL + (size_t)c * CHUNK + tid] = vals[tid];
  if (tid == 0) chunk_tot[b * NCHUNK + c] = vals[0]; // whole-chunk total
}

// Kernel 2: per batch, suffix-sum the 16 chunk totals and add the offset of
// all later chunks to each q entry. ~2 MiB traffic total, negligible.
__global__ __launch_bounds__(256) void qval_offset_kernel(
    const float* __restrict__ chunk_tot, float* __restrict__ q) {
  const int b = blockIdx.x;
  const int tid = (int)threadIdx.x;
  __shared__ float offs[NCHUNK];
  if (tid == 0) {
    float run = 0.0f;
    for (int c = NCHUNK - 1; c >= 0; --c) {
      offs[c] = run;                 // sum of totals of chunks strictly after c
      run += chunk_tot[b * NCHUNK + c];
    }
  }
  __syncthreads();
  for (int i = 0; i < LL / 256; ++i) {
    const int l = i * 256 + tid;
    q[(size_t)b * LL + l] += offs[l >> 8]; // l / CHUNK
  }
}

extern "C" void kernel_launch(void* const* d_in, const int* in_sizes, int n_in,
                              void* d_out, int out_size, void* d_ws,
                              size_t ws_size, hipStream_t stream) {
  const float* states = (const float*)d_in[0];   // [B, L, D] fp32
  const float* w      = (const float*)d_in[1];   // [D] fp32
  const float* br     = (const float*)d_in[2];   // scalar fp32
  float* q            = (float*)d_out;           // [B, L] fp32
  float* chunk_tot    = (float*)d_ws;            // [B, NCHUNK] fp32 (4 KiB)

  qval_chunk_kernel<<<dim3(NCHUNK, BB), 256, 0, stream>>>(states, w, br, q,
                                                          chunk_tot);
  qval_offset_kernel<<<BB, 256, 0, stream>>>(chunk_tot, q);
}

// Round 2
// 356.796 us; speedup vs baseline: 1.0195x; 1.0195x over previous
//
#include <hip/hip_runtime.h>

// Problem constants (fixed by the reference): B=64, L=4096, D=256.
#define BB 64
#define LL 4096
#define DD 256
#define CHUNK 128
#define NCHUNK (LL / CHUNK) // 32

__device__ inline float dot4(float4 a, float4 b) {
  return a.x * b.x + a.y * b.y + a.z * b.z + a.w * b.w;
}

// Kernel 1: per (batch, 128-row chunk) block. 16 lanes per row (4 rows per
// wave-step, groups reduce in parallel -> 1 shuffle-op/row amortized), then a
// wave-0 shuffle suffix-scan over the 128 chunk values -> q; total -> chunk_tot.
__global__ __launch_bounds__(256) void qval_chunk_kernel(
    const float* __restrict__ states, const float* __restrict__ w,
    const float* __restrict__ b_reward, float* __restrict__ q,
    float* __restrict__ chunk_tot) {
  const int c = blockIdx.x;
  const int b = blockIdx.y;
  const int tid = (int)threadIdx.x;
  const int wave = tid >> 6;
  const int lane = tid & 63;
  const int grp = lane >> 4; // which of 4 rows this step
  const int sub = lane & 15; // position within row (16 lanes/row)

  __shared__ float vals[CHUNK];

  const float4* w4 = (const float4*)w;
  const float4 wv0 = w4[0 * 16 + sub];
  const float4 wv1 = w4[1 * 16 + sub];
  const float4 wv2 = w4[2 * 16 + sub];
  const float4 wv3 = w4[3 * 16 + sub];
  const float br = *b_reward;

  const float4* sp =
      (const float4*)(states + ((size_t)b * LL + (size_t)c * CHUNK) * DD);

  // Wave handles rows [wave*32, wave*32+32): 4 rows/step (one per grp),
  // unrolled 2 steps -> 8 float4 loads in flight per lane.
  for (int i0 = 0; i0 < 8; i0 += 2) {
    const int rA = wave * 32 + i0 * 4 + grp;
    const int rB = rA + 4;
    const float4* pA = sp + (size_t)rA * 64 + sub;
    const float4* pB = sp + (size_t)rB * 64 + sub;
    float4 a0 = pA[0], a1 = pA[16], a2 = pA[32], a3 = pA[48];
    float4 b0 = pB[0], b1 = pB[16], b2 = pB[32], b3 = pB[48];
    float dA = dot4(a0, wv0) + dot4(a1, wv1) + dot4(a2, wv2) + dot4(a3, wv3);
    float dB = dot4(b0, wv0) + dot4(b1, wv1) + dot4(b2, wv2) + dot4(b3, wv3);
    // 16-lane butterfly (masks <16 never cross the aligned 16-lane group).
    for (int m = 8; m >= 1; m >>= 1) {
      dA += __shfl_xor(dA, m);
      dB += __shfl_xor(dB, m);
    }
    if (sub == 0) {
      vals[rA] = dA + br;
      vals[rB] = dB + br;
    }
  }
  __syncthreads();

  // Wave 0: inclusive suffix scan of 128 values via pair trick.
  if (wave == 0) {
    const float p = vals[2 * lane];
    const float s = vals[2 * lane + 1];
    float pair = p + s;
    for (int off = 1; off < 64; off <<= 1) {
      float t = __shfl_down(pair, off);
      pair += (lane + off < 64) ? t : 0.0f;
    }
    float2 o;
    o.x = pair;      // suffix sum at position 2*lane
    o.y = pair - p;  // suffix sum at position 2*lane+1
    ((float2*)(q + (size_t)b * LL + (size_t)c * CHUNK))[lane] = o;
    if (lane == 0) chunk_tot[b * NCHUNK + c] = pair; // whole-chunk total
  }
}

// Kernel 2: per (quarter, batch) block — suffix-sum the 32 chunk totals
// (wave-0 shuffle scan) and add each chunk's "later chunks" offset to q.
__global__ __launch_bounds__(256) void qval_offset_kernel(
    const float* __restrict__ chunk_tot, float* __restrict__ q) {
  const int part = blockIdx.x; // 0..3
  const int b = blockIdx.y;
  const int tid = (int)threadIdx.x;
  const int lane = tid & 63;
  __shared__ float offs[NCHUNK];
  if (tid < 64) {
    float own = (lane < NCHUNK) ? chunk_tot[b * NCHUNK + lane] : 0.0f;
    float t = own;
    for (int off = 1; off < 64; off <<= 1) {
      float u = __shfl_down(t, off);
      t += (lane + off < 64) ? u : 0.0f;
    }
    if (lane < NCHUNK) offs[lane] = t - own; // exclusive suffix (chunks after)
  }
  __syncthreads();
  // This block updates 1024 floats = 256 float4 of batch b.
  const int f4 = part * 256 + tid;           // float4 index within row
  const float o = offs[(f4 * 4) >> 7];       // chunk = floatidx/128
  float4* qp = (float4*)(q + (size_t)b * LL);
  float4 v = qp[f4];
  v.x += o; v.y += o; v.z += o; v.w += o;
  qp[f4] = v;
}

extern "C" void kernel_launch(void* const* d_in, const int* in_sizes, int n_in,
                              void* d_out, int out_size, void* d_ws,
                              size_t ws_size, hipStream_t stream) {
  const float* states = (const float*)d_in[0]; // [B, L, D] fp32
  const float* w      = (const float*)d_in[1]; // [D] fp32
  const float* br     = (const float*)d_in[2]; // scalar fp32
  float* q            = (float*)d_out;         // [B, L] fp32
  float* chunk_tot    = (float*)d_ws;          // [B, NCHUNK] fp32 (8 KiB)

  qval_chunk_kernel<<<dim3(NCHUNK, BB), 256, 0, stream>>>(states, w, br, q,
                                                          chunk_tot);
  qval_offset_kernel<<<dim3(4, BB), 256, 0, stream>>>(chunk_tot, q);
}